// Round 2
// baseline (288.488 us; speedup 1.0000x reference)
//
#include <hip/hip_runtime.h>
#include <hip/hip_bf16.h>
#include <stdint.h>

typedef __bf16 bf16;
typedef __bf16 bf16x8 __attribute__((ext_vector_type(8)));
typedef __bf16 bf16x4 __attribute__((ext_vector_type(4)));
typedef float  f32x4  __attribute__((ext_vector_type(4)));

#define MROWS 131072   // B*H*W rows
#define YSTR  576      // q|k|v row stride in ws

__device__ __forceinline__ f32x4 mfma16(bf16x8 a, bf16x8 b, f32x4 c) {
    return __builtin_amdgcn_mfma_f32_16x16x32_bf16(a, b, c, 0, 0, 0);
}
__device__ __forceinline__ f32x4 zero4() {
    f32x4 z; z[0]=0.f; z[1]=0.f; z[2]=0.f; z[3]=0.f; return z;
}
__device__ __forceinline__ bf16x8 zero8() {
    bf16x8 z;
#pragma unroll
    for (int i = 0; i < 8; ++i) z[i] = (bf16)0.f;
    return z;
}

// ---------------- X fp32 -> bf16 ----------------
__global__ __launch_bounds__(256) void kx(const float* __restrict__ X, bf16* __restrict__ Xb) {
    size_t i = ((size_t)blockIdx.x * 256 + threadIdx.x) * 8;   // 8 elems/thread
    f32x4 a = *(const f32x4*)(X + i);
    f32x4 b = *(const f32x4*)(X + i + 4);
    bf16x4 oa, ob;
#pragma unroll
    for (int e = 0; e < 4; ++e) { oa[e] = (bf16)a[e]; ob[e] = (bf16)b[e]; }
    *(bf16x4*)(Xb + i) = oa;
    *(bf16x4*)(Xb + i + 4) = ob;
}

// ---------------- weight transpose fp32 -> bf16: Wt[col][k] (k-contiguous) ----
// col 0..191 -> Wq col; 192..383 -> Wkv col (k); 384..575 -> Wkv col+192 (v)
// col 576..767 -> Wproj transpose
__global__ void kw_transpose(const float* __restrict__ Wq, const float* __restrict__ Wkv,
                             const float* __restrict__ Wp, bf16* __restrict__ Wt,
                             bf16* __restrict__ Wpt) {
    int col = blockIdx.x;
    int k = threadIdx.x;  // 192
    if (col < 192)      Wt[col * 192 + k] = (bf16)Wq[k * 192 + col];
    else if (col < 576) Wt[col * 192 + k] = (bf16)Wkv[k * 384 + (col - 192)];
    else                Wpt[(col - 576) * 192 + k] = (bf16)Wp[k * 192 + (col - 576)];
}

// ---------------- QKV GEMM: Y = Xb @ [Wq | Wkv], LDS-free MFMA ----------------
// grid (6, 1024): x = N-block (96 cols), y = M-block (128 rows). 4 waves, each 32xN96.
__global__ __launch_bounds__(256) void kqkv(const bf16* __restrict__ X,
                                            const bf16* __restrict__ Wt,
                                            bf16* __restrict__ Y) {
    int nb = blockIdx.x;
    int mb = blockIdx.y;
    int w  = threadIdx.x >> 6;
    int l  = threadIdx.x & 63;
    int li = l & 15, lk = l >> 4;
    int rb = mb * 128 + w * 32;
    int cb = nb * 96;

    bf16x8 a[2][6];
#pragma unroll
    for (int it = 0; it < 2; ++it)
#pragma unroll
        for (int ks = 0; ks < 6; ++ks)
            a[it][ks] = *(const bf16x8*)(X + (size_t)(rb + it * 16 + li) * 192 + ks * 32 + lk * 8);

    f32x4 acc[2][6];
#pragma unroll
    for (int it = 0; it < 2; ++it)
#pragma unroll
        for (int nt = 0; nt < 6; ++nt) acc[it][nt] = zero4();

#pragma unroll
    for (int nt = 0; nt < 6; ++nt) {
#pragma unroll
        for (int ks = 0; ks < 6; ++ks) {
            bf16x8 b = *(const bf16x8*)(Wt + (size_t)(cb + nt * 16 + li) * 192 + ks * 32 + lk * 8);
            acc[0][nt] = mfma16(a[0][ks], b, acc[0][nt]);
            acc[1][nt] = mfma16(a[1][ks], b, acc[1][nt]);
        }
    }
#pragma unroll
    for (int it = 0; it < 2; ++it)
#pragma unroll
        for (int nt = 0; nt < 6; ++nt)
#pragma unroll
            for (int r = 0; r < 4; ++r)
                Y[(size_t)(rb + it * 16 + lk * 4 + r) * YSTR + cb + nt * 16 + li] =
                    (bf16)acc[it][nt][r];
}

// ---------------- windowed attention ----------------
// grid (4096, 2): x = img*512 + window, y = branch. 4 waves = 4 heads. N=32 tokens, c=24.
__global__ __launch_bounds__(256) void kattn(const bf16* __restrict__ Y, bf16* __restrict__ Out) {
    const int branch = blockIdx.y;
    const int bw = blockIdx.x;
    const int img = bw >> 9;
    const int widx = bw & 511;
    const int wh = branch ? 8 : 4, ww = branch ? 4 : 8;
    const int lww = branch ? 2 : 3;           // log2(ww)
    const int lnv = branch ? 5 : 4;           // log2(128/ww)
    const int sh = wh >> 1, sw = ww >> 1;
    const int wa = widx >> lnv;
    const int wb = widx & ((128 >> lww) - 1);

    __shared__ int pix[32];
    __shared__ int rid[32];
    __shared__ bf16 vt[4][24][40];            // [head][c][token], padded stride 40
    __shared__ bf16 pl[4][32][40];            // [head][i][j]

    const int tid = threadIdx.x;
    if (tid < 32) {
        int ih = tid >> lww, iw = tid & (ww - 1);
        int hh = wa * wh + ih, wp = wb * ww + iw;          // rolled coords
        int hreg = (hh >= 128 - wh) + (hh >= 128 - sh);
        int wreg = (wp >= 128 - ww) + (wp >= 128 - sw);
        rid[tid] = hreg * 3 + wreg;
        int srh = (hh + sh) & 127, srw = (wp + sw) & 127;  // source pixel
        pix[tid] = img * 16384 + srh * 128 + srw;
    }
    __syncthreads();

    // stage V transposed: vt[head][c][token]
    for (int idx = tid; idx < 768; idx += 256) {
        int j = idx / 24;
        int c4 = (idx % 24) * 4;
        bf16x4 v = *(const bf16x4*)(Y + (size_t)pix[j] * YSTR + 384 + branch * 96 + c4);
        int hd = c4 / 24, cc = c4 % 24;
#pragma unroll
        for (int e = 0; e < 4; ++e) vt[hd][cc + e][j] = v[e];
    }
    __syncthreads();

    const int hd = tid >> 6;
    const int l = tid & 63, li = l & 15, lk = l >> 4;
    const int chq = branch * 96 + hd * 24;

    // Q/K fragments straight from global (k-contiguous); lane-group 3 = K-pad -> zero
    bf16x8 aq[2], bk[2];
#pragma unroll
    for (int t = 0; t < 2; ++t) {
        if (lk < 3) {
            aq[t] = *(const bf16x8*)(Y + (size_t)pix[t * 16 + li] * YSTR + chq + lk * 8);
            bk[t] = *(const bf16x8*)(Y + (size_t)pix[t * 16 + li] * YSTR + 192 + chq + lk * 8);
        } else {
            aq[t] = zero8();
            bk[t] = zero8();
        }
    }
    f32x4 s[2][2];
#pragma unroll
    for (int it = 0; it < 2; ++it)
#pragma unroll
        for (int jt = 0; jt < 2; ++jt) s[it][jt] = mfma16(aq[it], bk[jt], zero4());

    const float scale = 0.2041241452319315f;  // 24^-0.5
    const int r0 = lk * 4;
    const int rj0 = rid[li], rj1 = rid[16 + li];
#pragma unroll
    for (int it = 0; it < 2; ++it) {
#pragma unroll
        for (int r = 0; r < 4; ++r) {
            int i = it * 16 + r0 + r;
            int ri = rid[i];
            float v0 = s[it][0][r] * scale + ((ri != rj0) ? -100.f : 0.f);
            float v1 = s[it][1][r] * scale + ((ri != rj1) ? -100.f : 0.f);
            float m = fmaxf(v0, v1);
#pragma unroll
            for (int d = 1; d < 16; d <<= 1) m = fmaxf(m, __shfl_xor(m, d));
            float e0 = __expf(v0 - m), e1 = __expf(v1 - m);
            float sm = e0 + e1;
#pragma unroll
            for (int d = 1; d < 16; d <<= 1) sm += __shfl_xor(sm, d);
            float inv = 1.f / sm;
            pl[hd][i][li] = (bf16)(e0 * inv);
            pl[hd][i][16 + li] = (bf16)(e1 * inv);
        }
    }
    __syncthreads();

    // O = P @ V
    bf16x8 ap[2], bv[2];
#pragma unroll
    for (int it = 0; it < 2; ++it)
        ap[it] = *(const bf16x8*)(&pl[hd][it * 16 + li][lk * 8]);
#pragma unroll
    for (int ct = 0; ct < 2; ++ct) {
        int col = ct * 16 + li;
        if (col > 23) col = 23;               // clamp: garbage cols never written
        bv[ct] = *(const bf16x8*)(&vt[hd][col][lk * 8]);
    }
    f32x4 o[2][2];
#pragma unroll
    for (int it = 0; it < 2; ++it)
#pragma unroll
        for (int ct = 0; ct < 2; ++ct) o[it][ct] = mfma16(ap[it], bv[ct], zero4());

#pragma unroll
    for (int it = 0; it < 2; ++it)
#pragma unroll
        for (int ct = 0; ct < 2; ++ct) {
            int col = ct * 16 + li;
            if (col < 24) {
#pragma unroll
                for (int r = 0; r < 4; ++r) {
                    int i = it * 16 + r0 + r;
                    Out[(size_t)pix[i] * 192 + chq + col] = (bf16)o[it][ct][r];
                }
            }
        }
}

// ---------------- output projection: fp32 out = Ab @ Wproj + bias ----------------
// grid 1024, 4 waves; wave = 32 rows x full N=192.
__global__ __launch_bounds__(256) void kproj(const bf16* __restrict__ Ab,
                                             const bf16* __restrict__ Wpt,
                                             const float* __restrict__ bias,
                                             float* __restrict__ Out) {
    int w = threadIdx.x >> 6, l = threadIdx.x & 63;
    int li = l & 15, lk = l >> 4;
    int rb = blockIdx.x * 128 + w * 32;

    bf16x8 a[2][6];
#pragma unroll
    for (int it = 0; it < 2; ++it)
#pragma unroll
        for (int ks = 0; ks < 6; ++ks)
            a[it][ks] = *(const bf16x8*)(Ab + (size_t)(rb + it * 16 + li) * 192 + ks * 32 + lk * 8);

    f32x4 acc[2][12];
#pragma unroll
    for (int it = 0; it < 2; ++it)
#pragma unroll
        for (int nt = 0; nt < 12; ++nt) acc[it][nt] = zero4();

#pragma unroll
    for (int nt = 0; nt < 12; ++nt) {
#pragma unroll
        for (int ks = 0; ks < 6; ++ks) {
            bf16x8 b = *(const bf16x8*)(Wpt + (size_t)(nt * 16 + li) * 192 + ks * 32 + lk * 8);
            acc[0][nt] = mfma16(a[0][ks], b, acc[0][nt]);
            acc[1][nt] = mfma16(a[1][ks], b, acc[1][nt]);
        }
    }
#pragma unroll
    for (int nt = 0; nt < 12; ++nt) {
        float bv = bias[nt * 16 + li];
#pragma unroll
        for (int it = 0; it < 2; ++it)
#pragma unroll
            for (int r = 0; r < 4; ++r)
                Out[(size_t)(rb + it * 16 + lk * 4 + r) * 192 + nt * 16 + li] =
                    acc[it][nt][r] + bv;
    }
}

extern "C" void kernel_launch(void* const* d_in, const int* in_sizes, int n_in,
                              void* d_out, int out_size, void* d_ws, size_t ws_size,
                              hipStream_t stream) {
    const float* x    = (const float*)d_in[0];
    const float* Wq   = (const float*)d_in[1];
    const float* Wkv  = (const float*)d_in[2];
    const float* Wp   = (const float*)d_in[3];
    const float* bias = (const float*)d_in[4];
    float* out = (float*)d_out;

    bf16* Y   = (bf16*)d_ws;                       // 131072 x 576 bf16 = 144 MiB
    bf16* Xb  = Y + (size_t)MROWS * YSTR;          // 131072 x 192 bf16 = 48 MiB
    bf16* Ab  = Xb;                                // aliased: Xb dead after kqkv
    bf16* Wt  = Xb + (size_t)MROWS * 192;          // 576 x 192
    bf16* Wpt = Wt + 576 * 192;                    // 192 x 192

    hipLaunchKernelGGL(kx, dim3(MROWS * 192 / (256 * 8)), dim3(256), 0, stream, x, Xb);
    hipLaunchKernelGGL(kw_transpose, dim3(768), dim3(192), 0, stream, Wq, Wkv, Wp, Wt, Wpt);
    hipLaunchKernelGGL(kqkv, dim3(6, 1024), dim3(256), 0, stream, Xb, Wt, Y);
    hipLaunchKernelGGL(kattn, dim3(4096, 2), dim3(256), 0, stream, Y, Ab);
    hipLaunchKernelGGL(kproj, dim3(1024), dim3(256), 0, stream, Ab, Wpt, bias, out);
}

// Round 3
// 202.722 us; speedup vs baseline: 1.4231x; 1.4231x over previous
//
#include <hip/hip_runtime.h>
#include <hip/hip_bf16.h>
#include <stdint.h>

typedef __bf16 bf16;
typedef __bf16 bf16x8 __attribute__((ext_vector_type(8)));
typedef __bf16 bf16x4 __attribute__((ext_vector_type(4)));
typedef float  f32x4  __attribute__((ext_vector_type(4)));

#define MROWS 131072   // B*H*W rows
#define YSTR  576      // q|k|v row stride in ws
#define BSTR  200      // LDS B-panel row stride (bf16): 100 dw -> conflict-optimal b128

__device__ __forceinline__ f32x4 mfma16(bf16x8 a, bf16x8 b, f32x4 c) {
    return __builtin_amdgcn_mfma_f32_16x16x32_bf16(a, b, c, 0, 0, 0);
}
__device__ __forceinline__ f32x4 zero4() {
    f32x4 z; z[0]=0.f; z[1]=0.f; z[2]=0.f; z[3]=0.f; return z;
}
__device__ __forceinline__ bf16x8 zero8() {
    bf16x8 z;
#pragma unroll
    for (int i = 0; i < 8; ++i) z[i] = (bf16)0.f;
    return z;
}

// ---------------- X fp32 -> bf16 ----------------
__global__ __launch_bounds__(256) void kx(const float* __restrict__ X, bf16* __restrict__ Xb) {
    size_t i = ((size_t)blockIdx.x * 256 + threadIdx.x) * 8;   // 8 elems/thread
    f32x4 a = *(const f32x4*)(X + i);
    f32x4 b = *(const f32x4*)(X + i + 4);
    bf16x4 oa, ob;
#pragma unroll
    for (int e = 0; e < 4; ++e) { oa[e] = (bf16)a[e]; ob[e] = (bf16)b[e]; }
    *(bf16x4*)(Xb + i) = oa;
    *(bf16x4*)(Xb + i + 4) = ob;
}

// ---------------- weight transpose fp32 -> bf16: Wt[col][k] (k-contiguous) ----
__global__ void kw_transpose(const float* __restrict__ Wq, const float* __restrict__ Wkv,
                             const float* __restrict__ Wp, bf16* __restrict__ Wt,
                             bf16* __restrict__ Wpt) {
    int col = blockIdx.x;
    int k = threadIdx.x;  // 192
    if (col < 192)      Wt[col * 192 + k] = (bf16)Wq[k * 192 + col];
    else if (col < 576) Wt[col * 192 + k] = (bf16)Wkv[k * 384 + (col - 192)];
    else                Wpt[(col - 576) * 192 + k] = (bf16)Wp[k * 192 + (col - 576)];
}

// ---------------- QKV GEMM: Y = Xb @ [Wq | Wkv], LDS-staged B panel ----------
// grid (6, 1024): x = N-panel (96 cols), y = M-block (128 rows). 4 waves x 32 rows.
// Swapped-operand MFMA: acc[it][nt] holds D[n on reg axis][m on lane axis].
__global__ __launch_bounds__(256) void kqkv(const bf16* __restrict__ X,
                                            const bf16* __restrict__ Wt,
                                            bf16* __restrict__ Y) {
    __shared__ __align__(16) bf16 Bs[96][BSTR];
    const int nb = blockIdx.x, mb = blockIdx.y;
    const int tid = threadIdx.x;
    const int w = tid >> 6, l = tid & 63, li = l & 15, lk = l >> 4;
    const int rb = mb * 128 + w * 32;
    const int cb = nb * 96;

    // stage B panel: 96 rows x 192 k, 2304 bf16x8 chunks / 256 threads = 9 each
#pragma unroll
    for (int i = 0; i < 9; ++i) {
        int c = i * 256 + tid;
        int r = c / 24, col = (c % 24) * 8;
        *(bf16x8*)&Bs[r][col] = *(const bf16x8*)(Wt + (size_t)(cb + r) * 192 + col);
    }

    // A fragments from global (rows gathered per lane)
    bf16x8 a[2][6];
#pragma unroll
    for (int it = 0; it < 2; ++it)
#pragma unroll
        for (int ks = 0; ks < 6; ++ks)
            a[it][ks] = *(const bf16x8*)(X + (size_t)(rb + it * 16 + li) * 192 + ks * 32 + lk * 8);

    __syncthreads();

    f32x4 acc[2][6];
#pragma unroll
    for (int it = 0; it < 2; ++it)
#pragma unroll
        for (int nt = 0; nt < 6; ++nt) acc[it][nt] = zero4();

#pragma unroll
    for (int nt = 0; nt < 6; ++nt) {
#pragma unroll
        for (int ks = 0; ks < 6; ++ks) {
            bf16x8 b = *(const bf16x8*)&Bs[nt * 16 + li][ks * 32 + lk * 8];
            acc[0][nt] = mfma16(b, a[0][ks], acc[0][nt]);
            acc[1][nt] = mfma16(b, a[1][ks], acc[1][nt]);
        }
    }

    // D[n=nt*16+lk*4+r][m=rb+it*16+li] -> 8B packed stores
#pragma unroll
    for (int it = 0; it < 2; ++it)
#pragma unroll
        for (int nt = 0; nt < 6; ++nt) {
            bf16x4 pk;
#pragma unroll
            for (int r = 0; r < 4; ++r) pk[r] = (bf16)acc[it][nt][r];
            *(bf16x4*)(Y + (size_t)(rb + it * 16 + li) * YSTR + cb + nt * 16 + lk * 4) = pk;
        }
}

// ---------------- windowed attention ----------------
// grid (4096, 2): x = img*512 + window, y = branch. 4 waves = 4 heads. N=32 tokens, c=24.
__global__ __launch_bounds__(256) void kattn(const bf16* __restrict__ Y, bf16* __restrict__ Out) {
    const int branch = blockIdx.y;
    const int bw = blockIdx.x;
    const int img = bw >> 9;
    const int widx = bw & 511;
    const int wh = branch ? 8 : 4, ww = branch ? 4 : 8;
    const int lww = branch ? 2 : 3;           // log2(ww)
    const int lnv = branch ? 5 : 4;           // log2(128/ww)
    const int sh = wh >> 1, sw = ww >> 1;
    const int wa = widx >> lnv;
    const int wb = widx & ((128 >> lww) - 1);

    __shared__ int pix[32];
    __shared__ int rid[32];
    __shared__ bf16 vt[4][24][40];            // [head][c][token], padded stride 40
    __shared__ bf16 pl[4][32][40];            // [head][i][j]
    __shared__ __align__(16) bf16 ob[32][104];// [token][col 0..95], stride 104 (16B-aligned rows)

    const int tid = threadIdx.x;
    if (tid < 32) {
        int ih = tid >> lww, iw = tid & (ww - 1);
        int hh = wa * wh + ih, wp = wb * ww + iw;          // rolled coords
        int hreg = (hh >= 128 - wh) + (hh >= 128 - sh);
        int wreg = (wp >= 128 - ww) + (wp >= 128 - sw);
        rid[tid] = hreg * 3 + wreg;
        int srh = (hh + sh) & 127, srw = (wp + sw) & 127;  // source pixel
        pix[tid] = img * 16384 + srh * 128 + srw;
    }
    __syncthreads();

    // stage V transposed: vt[head][c][token]
    for (int idx = tid; idx < 768; idx += 256) {
        int j = idx / 24;
        int c4 = (idx % 24) * 4;
        bf16x4 v = *(const bf16x4*)(Y + (size_t)pix[j] * YSTR + 384 + branch * 96 + c4);
        int hd = c4 / 24, cc = c4 % 24;
#pragma unroll
        for (int e = 0; e < 4; ++e) vt[hd][cc + e][j] = v[e];
    }
    __syncthreads();

    const int hd = tid >> 6;
    const int l = tid & 63, li = l & 15, lk = l >> 4;
    const int chq = branch * 96 + hd * 24;

    // Q/K fragments straight from global (k-contiguous); lane-group 3 = K-pad -> zero
    bf16x8 aq[2], bk[2];
#pragma unroll
    for (int t = 0; t < 2; ++t) {
        if (lk < 3) {
            aq[t] = *(const bf16x8*)(Y + (size_t)pix[t * 16 + li] * YSTR + chq + lk * 8);
            bk[t] = *(const bf16x8*)(Y + (size_t)pix[t * 16 + li] * YSTR + 192 + chq + lk * 8);
        } else {
            aq[t] = zero8();
            bk[t] = zero8();
        }
    }
    f32x4 s[2][2];
#pragma unroll
    for (int it = 0; it < 2; ++it)
#pragma unroll
        for (int jt = 0; jt < 2; ++jt) s[it][jt] = mfma16(aq[it], bk[jt], zero4());

    const float scale = 0.2041241452319315f;  // 24^-0.5
    const int r0 = lk * 4;
    const int rj0 = rid[li], rj1 = rid[16 + li];
#pragma unroll
    for (int it = 0; it < 2; ++it) {
#pragma unroll
        for (int r = 0; r < 4; ++r) {
            int i = it * 16 + r0 + r;
            int ri = rid[i];
            float v0 = s[it][0][r] * scale + ((ri != rj0) ? -100.f : 0.f);
            float v1 = s[it][1][r] * scale + ((ri != rj1) ? -100.f : 0.f);
            float m = fmaxf(v0, v1);
#pragma unroll
            for (int d = 1; d < 16; d <<= 1) m = fmaxf(m, __shfl_xor(m, d));
            float e0 = __expf(v0 - m), e1 = __expf(v1 - m);
            float sm = e0 + e1;
#pragma unroll
            for (int d = 1; d < 16; d <<= 1) sm += __shfl_xor(sm, d);
            float inv = 1.f / sm;
            pl[hd][i][li] = (bf16)(e0 * inv);
            pl[hd][i][16 + li] = (bf16)(e1 * inv);
        }
    }
    __syncthreads();

    // O = P @ V
    bf16x8 ap[2], bv[2];
#pragma unroll
    for (int it = 0; it < 2; ++it)
        ap[it] = *(const bf16x8*)(&pl[hd][it * 16 + li][lk * 8]);
#pragma unroll
    for (int ct = 0; ct < 2; ++ct) {
        int col = ct * 16 + li;
        if (col > 23) col = 23;               // clamp: garbage cols never written
        bv[ct] = *(const bf16x8*)(&vt[hd][col][lk * 8]);
    }
    f32x4 o[2][2];
#pragma unroll
    for (int it = 0; it < 2; ++it)
#pragma unroll
        for (int ct = 0; ct < 2; ++ct) o[it][ct] = mfma16(ap[it], bv[ct], zero4());

    // stage O in LDS, then coalesced bf16x8 writeback
#pragma unroll
    for (int it = 0; it < 2; ++it)
#pragma unroll
        for (int ct = 0; ct < 2; ++ct) {
            int col = ct * 16 + li;
            if (col < 24) {
#pragma unroll
                for (int r = 0; r < 4; ++r)
                    ob[it * 16 + r0 + r][hd * 24 + col] = (bf16)o[it][ct][r];
            }
        }
    __syncthreads();
    for (int c = tid; c < 384; c += 256) {    // 32 tokens x 12 chunks of 8
        int row = c / 12, ch = c % 12;
        *(bf16x8*)(Out + (size_t)pix[row] * 192 + branch * 96 + ch * 8) =
            *(const bf16x8*)&ob[row][ch * 8];
    }
}

// ---------------- output projection: fp32 out = Ab @ Wproj + bias --------------
// grid (2, 1024): x = N-panel (96 cols), y = M-block (128 rows). LDS-staged B.
__global__ __launch_bounds__(256) void kproj(const bf16* __restrict__ Ab,
                                             const bf16* __restrict__ Wpt,
                                             const float* __restrict__ bias,
                                             float* __restrict__ Out) {
    __shared__ __align__(16) bf16 Bs[96][BSTR];
    const int nb = blockIdx.x, mb = blockIdx.y;
    const int tid = threadIdx.x;
    const int w = tid >> 6, l = tid & 63, li = l & 15, lk = l >> 4;
    const int rb = mb * 128 + w * 32;
    const int cb = nb * 96;

#pragma unroll
    for (int i = 0; i < 9; ++i) {
        int c = i * 256 + tid;
        int r = c / 24, col = (c % 24) * 8;
        *(bf16x8*)&Bs[r][col] = *(const bf16x8*)(Wpt + (size_t)(cb + r) * 192 + col);
    }

    bf16x8 a[2][6];
#pragma unroll
    for (int it = 0; it < 2; ++it)
#pragma unroll
        for (int ks = 0; ks < 6; ++ks)
            a[it][ks] = *(const bf16x8*)(Ab + (size_t)(rb + it * 16 + li) * 192 + ks * 32 + lk * 8);

    __syncthreads();

    f32x4 acc[2][6];
#pragma unroll
    for (int it = 0; it < 2; ++it)
#pragma unroll
        for (int nt = 0; nt < 6; ++nt) acc[it][nt] = zero4();

#pragma unroll
    for (int nt = 0; nt < 6; ++nt) {
#pragma unroll
        for (int ks = 0; ks < 6; ++ks) {
            bf16x8 b = *(const bf16x8*)&Bs[nt * 16 + li][ks * 32 + lk * 8];
            acc[0][nt] = mfma16(b, a[0][ks], acc[0][nt]);
            acc[1][nt] = mfma16(b, a[1][ks], acc[1][nt]);
        }
    }

    // D[n][m]: row = rb+it*16+li, cols = cb+nt*16+lk*4+(0..3) -> f32x4 stores
#pragma unroll
    for (int nt = 0; nt < 6; ++nt) {
        f32x4 bv4 = *(const f32x4*)(bias + cb + nt * 16 + lk * 4);
#pragma unroll
        for (int it = 0; it < 2; ++it) {
            f32x4 ov = acc[it][nt];
#pragma unroll
            for (int r = 0; r < 4; ++r) ov[r] += bv4[r];
            *(f32x4*)(Out + (size_t)(rb + it * 16 + li) * 192 + cb + nt * 16 + lk * 4) = ov;
        }
    }
}

extern "C" void kernel_launch(void* const* d_in, const int* in_sizes, int n_in,
                              void* d_out, int out_size, void* d_ws, size_t ws_size,
                              hipStream_t stream) {
    const float* x    = (const float*)d_in[0];
    const float* Wq   = (const float*)d_in[1];
    const float* Wkv  = (const float*)d_in[2];
    const float* Wp   = (const float*)d_in[3];
    const float* bias = (const float*)d_in[4];
    float* out = (float*)d_out;

    bf16* Y   = (bf16*)d_ws;                       // 131072 x 576 bf16 = 144 MiB
    bf16* Xb  = Y + (size_t)MROWS * YSTR;          // 131072 x 192 bf16 = 48 MiB
    bf16* Ab  = Xb;                                // aliased: Xb dead after kqkv
    bf16* Wt  = Xb + (size_t)MROWS * 192;          // 576 x 192
    bf16* Wpt = Wt + 576 * 192;                    // 192 x 192

    hipLaunchKernelGGL(kx, dim3(MROWS * 192 / (256 * 8)), dim3(256), 0, stream, x, Xb);
    hipLaunchKernelGGL(kw_transpose, dim3(768), dim3(192), 0, stream, Wq, Wkv, Wp, Wt, Wpt);
    hipLaunchKernelGGL(kqkv, dim3(6, 1024), dim3(256), 0, stream, Xb, Wt, Y);
    hipLaunchKernelGGL(kattn, dim3(4096, 2), dim3(256), 0, stream, Y, Ab);
    hipLaunchKernelGGL(kproj, dim3(2, 1024), dim3(256), 0, stream, Ab, Wpt, bias, out);
}